// Round 13
// baseline (318.434 us; speedup 1.0000x reference)
//
#include <hip/hip_runtime.h>
#include <math.h>

#define NN 50000
#define NE 800000
#define EP (NE + NN)        // edges including self loops
#define INC 128
#define HID 64
#define HEADS 4
#define C1 (HEADS * HID)    // 256
#define NEG 0.2f
#define EPSS 1e-16f

#define SCHUNK 512
#define NSB ((NN + SCHUNK - 1) / SCHUNK)   // 98

#define KP1 136             // gemm1 W1^T LDS stride
#define KP2 264             // gemm2 W2^T LDS stride
typedef __attribute__((ext_vector_type(8))) short bf16x8;
typedef __attribute__((ext_vector_type(4))) float f32x4;

// ---------- bf16 helpers ----------
__device__ __forceinline__ unsigned short f2bf(float f) {
    unsigned u = __float_as_uint(f);
    unsigned r = (u + 0x7FFFu + ((u >> 16) & 1u)) >> 16;
    return (unsigned short)r;
}
__device__ __forceinline__ float bf2f(unsigned short b) {
    return __uint_as_float(((unsigned)b) << 16);
}

// ================= CSR build (count merged into prep_all) =================
__global__ __launch_bounds__(SCHUNK) void scan_partial(const int* __restrict__ counts,
                                                       int* __restrict__ bsum) {
    __shared__ int lds[SCHUNK];
    int i = blockIdx.x * SCHUNK + threadIdx.x;
    lds[threadIdx.x] = (i < NN) ? counts[i] : 0;
    __syncthreads();
    for (int off = SCHUNK / 2; off > 0; off >>= 1) {
        if (threadIdx.x < off) lds[threadIdx.x] += lds[threadIdx.x + off];
        __syncthreads();
    }
    if (threadIdx.x == 0) bsum[blockIdx.x] = lds[0];
}

__global__ void scan_top(int* __restrict__ bsum, int* __restrict__ rowptr) {
    __shared__ int lds[NSB];
    int t = threadIdx.x;
    if (t < NSB) lds[t] = bsum[t];
    __syncthreads();
    if (t == 0) {
        int acc = 0;
        for (int i = 0; i < NSB; ++i) { int v = lds[i]; lds[i] = acc; acc += v; }
        rowptr[NN] = acc;   // == EP
    }
    __syncthreads();
    if (t < NSB) bsum[t] = lds[t];
}

__global__ __launch_bounds__(SCHUNK) void scan_final(const int* __restrict__ counts,
                                                     const int* __restrict__ bsum,
                                                     int* __restrict__ rowptr,
                                                     int* __restrict__ cursor) {
    __shared__ int lds[SCHUNK];
    int i = blockIdx.x * SCHUNK + threadIdx.x;
    int v = (i < NN) ? counts[i] : 0;
    lds[threadIdx.x] = v;
    __syncthreads();
    for (int off = 1; off < SCHUNK; off <<= 1) {
        int t = (threadIdx.x >= off) ? lds[threadIdx.x - off] : 0;
        __syncthreads();
        lds[threadIdx.x] += t;
        __syncthreads();
    }
    if (i < NN) {
        int excl = lds[threadIdx.x] - v + bsum[blockIdx.x];
        rowptr[i] = excl;
        cursor[i] = excl;
    }
}

__global__ void csr_fill(const int* __restrict__ ei, int* __restrict__ cursor,
                         int* __restrict__ csr_src, int* __restrict__ csr_dst) {
    int e = blockIdx.x * 256 + threadIdx.x;
    if (e >= EP) return;
    int s, d;
    if (e < NE) { s = ei[e]; d = ei[NE + e]; } else { s = d = e - NE; }
    int pos = atomicAdd(&cursor[d], 1);
    csr_src[pos] = s;
    csr_dst[pos] = d;
}

// ================= merged weight prep + edge count =================
// region 0: W1^T  -> w1h/w1l   [256 cols][128 k]
// region 1: W2^T  -> w2h/w2l   [64 cols][256 k]
// region 2: mW1 fragment-linear -> wFh/wFl  [kk][ct][lane][8]  (K=0..127)
// region 3: edge count
#define PREP_N0 (C1 * INC)
#define PREP_N1 (HID * C1)
#define PREP_N2 (4 * 4 * 64 * 8)   // 8192
#define PREP_TOT (PREP_N0 + PREP_N1 + PREP_N2)
__global__ void prep_all(const float* __restrict__ mW1, const float* __restrict__ W1,
                         const float* __restrict__ W2, const int* __restrict__ ei,
                         unsigned short* __restrict__ w1h, unsigned short* __restrict__ w1l,
                         unsigned short* __restrict__ w2h, unsigned short* __restrict__ w2l,
                         unsigned short* __restrict__ wFh, unsigned short* __restrict__ wFl,
                         int* __restrict__ counts) {
    int i = blockIdx.x * 256 + threadIdx.x;
    if (i < PREP_N0) {
        int c = i >> 7, k = i & 127;
        float f = W1[k * C1 + c];
        unsigned short h = f2bf(f);
        w1h[i] = h; w1l[i] = f2bf(f - bf2f(h));
        return;
    }
    i -= PREP_N0;
    if (i < PREP_N1) {
        int c = i >> 8, k = i & 255;
        float f = W2[k * HID + c];
        unsigned short h = f2bf(f);
        w2h[i] = h; w2l[i] = f2bf(f - bf2f(h));
        return;
    }
    i -= PREP_N1;
    if (i < PREP_N2) {
        int kk = i >> 11;
        int ct = (i >> 9) & 3;
        int l  = (i >> 3) & 63;
        int j  = i & 7;
        int cl = l & 15, g = l >> 4;
        int k   = kk * 32 + g * 8 + j;      // < 128
        int col = ct * 16 + cl;
        float f = mW1[k * 64 + col];
        unsigned short h = f2bf(f);
        wFh[i] = h;
        wFl[i] = f2bf(f - bf2f(h));
        return;
    }
    i -= PREP_N2;
    if (i < EP) {
        int d = (i < NE) ? ei[NE + i] : (i - NE);
        atomicAdd(&counts[d], 1);
    }
}

// ================= edge softmax weights (precomputed once per edge) ==========
__global__ void edge_w1k(const int* __restrict__ csr_src, const int* __restrict__ csr_dst,
                         const float* __restrict__ as1, const float* __restrict__ ad1,
                         float* __restrict__ w1e) {
    int i = blockIdx.x * 256 + threadIdx.x;
    if (i >= EP) return;
    int s = csr_src[i], d = csr_dst[i];
    float4 a = *(const float4*)(as1 + s * 4);
    float4 b = *(const float4*)(ad1 + d * 4);
    float4 o;
    float t;
    t = a.x + b.x; t = t > 0.f ? t : NEG * t; o.x = __expf(t);
    t = a.y + b.y; t = t > 0.f ? t : NEG * t; o.y = __expf(t);
    t = a.z + b.z; t = t > 0.f ? t : NEG * t; o.z = __expf(t);
    t = a.w + b.w; t = t > 0.f ? t : NEG * t; o.w = __expf(t);
    *(float4*)(w1e + (size_t)i * 4) = o;
}

__global__ void edge_w2k(const int* __restrict__ csr_src, const int* __restrict__ csr_dst,
                         const float* __restrict__ as2, const float* __restrict__ ad2,
                         float* __restrict__ w2e) {
    int i = blockIdx.x * 256 + threadIdx.x;
    if (i >= EP) return;
    float t = as2[csr_src[i]] + ad2[csr_dst[i]];
    t = t > 0.f ? t : NEG * t;
    w2e[i] = __expf(t);
}

// ================= GEMM1 via split-bf16 MFMA + att1 epilogue =================
__global__ __launch_bounds__(256) void gemm1_mfma(const float* __restrict__ x,
                                                  const unsigned short* __restrict__ w1h,
                                                  const unsigned short* __restrict__ w1l,
                                                  const float* __restrict__ att_s,
                                                  const float* __restrict__ att_d,
                                                  unsigned short* __restrict__ h1b,
                                                  float* __restrict__ as1,
                                                  float* __restrict__ ad1) {
    __shared__ unsigned short wH[64 * KP1];
    __shared__ unsigned short wL[64 * KP1];
    const int tid = threadIdx.x;
    const int n0 = blockIdx.x * 64;
    const int q  = blockIdx.y;

    for (int idx = tid; idx < 64 * 16; idx += 256) {
        int col = idx >> 4, ch = idx & 15;
        *(bf16x8*)(wH + col * KP1 + ch * 8) =
            *(const bf16x8*)(w1h + ((q * 64 + col) << 7) + ch * 8);
        *(bf16x8*)(wL + col * KP1 + ch * 8) =
            *(const bf16x8*)(w1l + ((q * 64 + col) << 7) + ch * 8);
    }

    const int w = tid >> 6, l = tid & 63;
    const int cl = l & 15, g = l >> 4, g8 = g * 8;
    const int na = min(n0 + w * 16 + cl, NN - 1);

    bf16x8 aH[4], aL[4];
#pragma unroll
    for (int kk = 0; kk < 4; ++kk) {
        const float* ap = x + (size_t)na * INC + kk * 32 + g8;
        float4 v0 = *(const float4*)ap;
        float4 v1 = *(const float4*)(ap + 4);
        float vv[8] = {v0.x, v0.y, v0.z, v0.w, v1.x, v1.y, v1.z, v1.w};
#pragma unroll
        for (int j = 0; j < 8; ++j) {
            unsigned short h = f2bf(vv[j]);
            aH[kk][j] = (short)h;
            aL[kk][j] = (short)f2bf(vv[j] - bf2f(h));
        }
    }

    f32x4 acc[4];
#pragma unroll
    for (int ct = 0; ct < 4; ++ct) acc[ct] = (f32x4){0.f, 0.f, 0.f, 0.f};

    __syncthreads();

#pragma unroll
    for (int kk = 0; kk < 4; ++kk) {
        const int ko = kk * 32 + g8;
#pragma unroll
        for (int ct = 0; ct < 4; ++ct) {
            const bf16x8 bH = *(const bf16x8*)(wH + (ct * 16 + cl) * KP1 + ko);
            const bf16x8 bL = *(const bf16x8*)(wL + (ct * 16 + cl) * KP1 + ko);
            acc[ct] = __builtin_amdgcn_mfma_f32_16x16x32_bf16(aH[kk], bH, acc[ct], 0, 0, 0);
            acc[ct] = __builtin_amdgcn_mfma_f32_16x16x32_bf16(aH[kk], bL, acc[ct], 0, 0, 0);
            acc[ct] = __builtin_amdgcn_mfma_f32_16x16x32_bf16(aL[kk], bH, acc[ct], 0, 0, 0);
        }
    }

    float asc[4], adc[4];
#pragma unroll
    for (int ct = 0; ct < 4; ++ct) {
        asc[ct] = att_s[q * 64 + ct * 16 + cl];
        adc[ct] = att_d[q * 64 + ct * 16 + cl];
    }

#pragma unroll
    for (int reg = 0; reg < 4; ++reg) {
        const int nd = n0 + w * 16 + g * 4 + reg;
        float sa = 0.f, sd = 0.f;
#pragma unroll
        for (int ct = 0; ct < 4; ++ct) {
            sa += acc[ct][reg] * asc[ct];
            sd += acc[ct][reg] * adc[ct];
        }
#pragma unroll
        for (int off = 8; off > 0; off >>= 1) {
            sa += __shfl_xor(sa, off);
            sd += __shfl_xor(sd, off);
        }
        if (nd < NN) {
#pragma unroll
            for (int ct = 0; ct < 4; ++ct)
                h1b[(size_t)nd * C1 + q * 64 + ct * 16 + cl] = f2bf(acc[ct][reg]);
            if (cl == 0) { as1[nd * 4 + q] = sa; ad1[nd * 4 + q] = sd; }
        }
    }
}

// ================= GEMM2: bf16-A x split-bf16-W MFMA + att2 epilogue =========
__global__ __launch_bounds__(256) void gemm2_mfma(const unsigned short* __restrict__ h1c,
                                                  const unsigned short* __restrict__ w2h,
                                                  const unsigned short* __restrict__ w2l,
                                                  const float* __restrict__ att_s,
                                                  const float* __restrict__ att_d,
                                                  unsigned short* __restrict__ h2b,
                                                  float* __restrict__ as2,
                                                  float* __restrict__ ad2) {
    __shared__ unsigned short wH[64 * KP2];
    __shared__ unsigned short wL[64 * KP2];
    const int tid = threadIdx.x;
    const int n0 = blockIdx.x * 64;

    for (int idx = tid; idx < 64 * 32; idx += 256) {
        int col = idx >> 5, ch = idx & 31;
        *(bf16x8*)(wH + col * KP2 + ch * 8) =
            *(const bf16x8*)(w2h + ((col) << 8) + ch * 8);
        *(bf16x8*)(wL + col * KP2 + ch * 8) =
            *(const bf16x8*)(w2l + ((col) << 8) + ch * 8);
    }

    const int w = tid >> 6, l = tid & 63;
    const int cl = l & 15, g = l >> 4, g8 = g * 8;
    const int na = min(n0 + w * 16 + cl, NN - 1);

    f32x4 acc[4];
#pragma unroll
    for (int ct = 0; ct < 4; ++ct) acc[ct] = (f32x4){0.f, 0.f, 0.f, 0.f};

    __syncthreads();

#pragma unroll
    for (int kk = 0; kk < 8; ++kk) {
        const bf16x8 aH = *(const bf16x8*)(h1c + (size_t)na * C1 + kk * 32 + g8);
        const int ko = kk * 32 + g8;
#pragma unroll
        for (int ct = 0; ct < 4; ++ct) {
            const bf16x8 bH = *(const bf16x8*)(wH + (ct * 16 + cl) * KP2 + ko);
            const bf16x8 bL = *(const bf16x8*)(wL + (ct * 16 + cl) * KP2 + ko);
            acc[ct] = __builtin_amdgcn_mfma_f32_16x16x32_bf16(aH, bH, acc[ct], 0, 0, 0);
            acc[ct] = __builtin_amdgcn_mfma_f32_16x16x32_bf16(aH, bL, acc[ct], 0, 0, 0);
        }
    }

    float asc[4], adc[4];
#pragma unroll
    for (int ct = 0; ct < 4; ++ct) {
        asc[ct] = att_s[ct * 16 + cl];
        adc[ct] = att_d[ct * 16 + cl];
    }

#pragma unroll
    for (int reg = 0; reg < 4; ++reg) {
        const int nd = n0 + w * 16 + g * 4 + reg;
        float sa = 0.f, sd = 0.f;
#pragma unroll
        for (int ct = 0; ct < 4; ++ct) {
            sa += acc[ct][reg] * asc[ct];
            sd += acc[ct][reg] * adc[ct];
        }
#pragma unroll
        for (int off = 8; off > 0; off >>= 1) {
            sa += __shfl_xor(sa, off);
            sd += __shfl_xor(sd, off);
        }
        if (nd < NN) {
#pragma unroll
            for (int ct = 0; ct < 4; ++ct)
                h2b[(size_t)nd * HID + ct * 16 + cl] = f2bf(acc[ct][reg]);
            if (cl == 0) { as2[nd] = sa; ad2[nd] = sd; }
        }
    }
}

// ================= conv1 aggregate: 2 nodes/wave, precomputed weights =========
__global__ __launch_bounds__(256) void conv1_agg(const int* __restrict__ rowptr,
                                                 const int* __restrict__ csr_src,
                                                 const float* __restrict__ w1e,
                                                 const unsigned short* __restrict__ h1b,
                                                 const float* __restrict__ b1,
                                                 unsigned short* __restrict__ h1c) {
    const int tid  = threadIdx.x;
    const int wid  = tid >> 6;
    const int l    = tid & 63;
    const int half = l >> 5;
    const int l32  = l & 31;
    const int node = blockIdx.x * 8 + wid * 2 + half;   // NN % 8 == 0
    const int hd   = l32 >> 3;
    const int beg = rowptr[node], end = rowptr[node + 1];

    float acc[8] = {0.f, 0.f, 0.f, 0.f, 0.f, 0.f, 0.f, 0.f};
    float sm = 0.f;
#pragma unroll 2
    for (int i = beg; i < end; ++i) {
        int s = csr_src[i];
        float w = w1e[(size_t)i * 4 + hd];
        bf16x8 hv = *(const bf16x8*)(h1b + (size_t)s * C1 + l32 * 8);
#pragma unroll
        for (int j = 0; j < 8; ++j)
            acc[j] += w * bf2f((unsigned short)hv[j]);
        sm += w;
    }
    const float rden = 1.f / (sm + EPSS);

    const float* bp = b1 + l32 * 8;
    bf16x8 ob;
#pragma unroll
    for (int j = 0; j < 8; ++j) {
        float o = acc[j] * rden + bp[j];
        o = o > 0.f ? o : (__expf(o) - 1.f);
        ob[j] = (short)f2bf(o);
    }
    *(bf16x8*)(h1c + (size_t)node * C1 + l32 * 8) = ob;
}

// ================= conv2 aggregate: 2 nodes/wave, precomputed weights =========
__global__ __launch_bounds__(256) void conv2_agg(const int* __restrict__ rowptr,
                                                 const int* __restrict__ csr_src,
                                                 const float* __restrict__ w2e,
                                                 const unsigned short* __restrict__ h2b,
                                                 const float* __restrict__ b2,
                                                 unsigned short* __restrict__ embb) {
    const int tid  = threadIdx.x;
    const int wid  = tid >> 6;
    const int l    = tid & 63;
    const int half = l >> 5;
    const int l32  = l & 31;
    const int node = blockIdx.x * 8 + wid * 2 + half;
    const int beg = rowptr[node], end = rowptr[node + 1];

    float a0 = 0.f, a1 = 0.f, sm = 0.f;
#pragma unroll 2
    for (int i = beg; i < end; ++i) {
        int s = csr_src[i];
        float w = w2e[i];
        unsigned hv = *(const unsigned*)(h2b + (size_t)s * HID + l32 * 2);
        a0 += w * bf2f((unsigned short)(hv & 0xFFFF));
        a1 += w * bf2f((unsigned short)(hv >> 16));
        sm += w;
    }
    const float rden = 1.f / (sm + EPSS);
    float o0 = a0 * rden + b2[l32 * 2];
    float o1 = a1 * rden + b2[l32 * 2 + 1];
    unsigned outw = (unsigned)f2bf(o0) | ((unsigned)f2bf(o1) << 16);
    *(unsigned*)(embb + (size_t)node * HID + l32 * 2) = outw;
}

// ================= edge MLP: 64 edges/wave, coalesced streamed W =============
// 4 sub-tiles of 16 edges share each B fragment (8 MFMAs per B load).
// W in fragment-linear layout wF[kk][ct][lane][8] -> 1KB coalesced wave loads.
__global__ __launch_bounds__(256, 2) void edge_mlp_mfma(const int* __restrict__ ei,
                                                        const unsigned short* __restrict__ embb,
                                                        const float* __restrict__ stats,
                                                        const unsigned short* __restrict__ wFh,
                                                        const unsigned short* __restrict__ wFl,
                                                        const float* __restrict__ mW1,
                                                        const float* __restrict__ mb1,
                                                        const float* __restrict__ mW2,
                                                        const float* __restrict__ mb2,
                                                        float* __restrict__ out) {
    const int l  = threadIdx.x & 63;
    const int cl = l & 15;
    const int g  = l >> 4;
    const int g8 = g * 8;

    // epilogue constants
    float w1s0[4], w1s1[4], w1s2[4], bia[4], w2a[4], w2b[4];
#pragma unroll
    for (int ct = 0; ct < 4; ++ct) {
        const int col = ct * 16 + cl;
        w1s0[ct] = mW1[128 * 64 + col];
        w1s1[ct] = mW1[129 * 64 + col];
        w1s2[ct] = mW1[130 * 64 + col];
        bia[ct] = mb1[col];
        w2a[ct] = mW2[col * 2 + 0];
        w2b[ct] = mW2[col * 2 + 1];
    }
    const float ob0 = mb2[0], ob1 = mb2[1];

    const int t = blockIdx.x * 4 + (threadIdx.x >> 6);   // 64-edge tile id, 0..12499

    // A gather: 4 sub-tiles x 4 k-chunks
    bf16x8 a[4][4];
#pragma unroll
    for (int s = 0; s < 4; ++s) {
        const int ge_a = t * 64 + s * 16 + cl;
        const int rn = ei[ge_a];
        const int cn = ei[NE + ge_a];
        const unsigned short* rp = embb + (size_t)rn * HID;
        const unsigned short* cp = embb + (size_t)cn * HID;
        a[s][0] = *(const bf16x8*)(rp + g8);
        a[s][1] = *(const bf16x8*)(rp + 32 + g8);
        a[s][2] = *(const bf16x8*)(cp + g8);
        a[s][3] = *(const bf16x8*)(cp + 32 + g8);
    }

    f32x4 acc[4][4];
#pragma unroll
    for (int s = 0; s < 4; ++s)
#pragma unroll
        for (int ct = 0; ct < 4; ++ct)
            acc[s][ct] = (f32x4){bia[ct], bia[ct], bia[ct], bia[ct]};

#pragma unroll
    for (int kk = 0; kk < 4; ++kk) {
#pragma unroll
        for (int ct = 0; ct < 4; ++ct) {
            const int fo = ((kk * 4 + ct) * 64 + l) * 8;
            const bf16x8 bH = *(const bf16x8*)(wFh + fo);
            const bf16x8 bL = *(const bf16x8*)(wFl + fo);
#pragma unroll
            for (int s = 0; s < 4; ++s) {
                acc[s][ct] = __builtin_amdgcn_mfma_f32_16x16x32_bf16(a[s][kk], bH, acc[s][ct], 0, 0, 0);
                acc[s][ct] = __builtin_amdgcn_mfma_f32_16x16x32_bf16(a[s][kk], bL, acc[s][ct], 0, 0, 0);
            }
        }
    }

    // epilogue: stats (exact f32) + layer 2 + 16-lane reduce + store
#pragma unroll
    for (int s = 0; s < 4; ++s) {
        const float* sp = stats + (size_t)(t * 64 + s * 16 + g * 4) * 3;
        float4 s0 = *(const float4*)(sp);
        float4 s1 = *(const float4*)(sp + 4);
        float4 s2 = *(const float4*)(sp + 8);
        float cst[12] = {s0.x, s0.y, s0.z, s0.w, s1.x, s1.y, s1.z, s1.w,
                         s2.x, s2.y, s2.z, s2.w};
#pragma unroll
        for (int reg = 0; reg < 4; ++reg) {
            float p0 = 0.f, p1 = 0.f;
#pragma unroll
            for (int ct = 0; ct < 4; ++ct) {
                float h = acc[s][ct][reg]
                        + cst[reg * 3 + 0] * w1s0[ct]
                        + cst[reg * 3 + 1] * w1s1[ct]
                        + cst[reg * 3 + 2] * w1s2[ct];
                h = fmaxf(h, 0.f);
                p0 += h * w2a[ct];
                p1 += h * w2b[ct];
            }
#pragma unroll
            for (int off = 8; off > 0; off >>= 1) {
                p0 += __shfl_xor(p0, off);
                p1 += __shfl_xor(p1, off);
            }
            if (cl == 0) {
                const int ge = t * 64 + s * 16 + g * 4 + reg;
                *(float2*)(out + (size_t)ge * 2) = make_float2(p0 + ob0, p1 + ob1);
            }
        }
    }
}

// ================= launcher =================
extern "C" void kernel_launch(void* const* d_in, const int* in_sizes, int n_in,
                              void* d_out, int out_size, void* d_ws, size_t ws_size,
                              hipStream_t stream) {
    const float* x      = (const float*)d_in[0];
    const int*   ei     = (const int*)d_in[1];
    const float* stats  = (const float*)d_in[2];
    const float* W1     = (const float*)d_in[3];
    const float* att_s1 = (const float*)d_in[4];
    const float* att_d1 = (const float*)d_in[5];
    const float* b1     = (const float*)d_in[6];
    const float* W2     = (const float*)d_in[7];
    const float* att_s2 = (const float*)d_in[8];
    const float* att_d2 = (const float*)d_in[9];
    const float* b2     = (const float*)d_in[10];
    const float* mW1    = (const float*)d_in[11];
    const float* mb1    = (const float*)d_in[12];
    const float* mW2    = (const float*)d_in[13];
    const float* mb2    = (const float*)d_in[14];
    float* out = (float*)d_out;
    float* ws  = (float*)d_ws;

    // f32-word-offset layout (no aliasing)
    int*   rowptr  = (int*)ws;                                 // NN+16
    int*   csr_src = rowptr + NN + 16;                         // EP
    int*   csr_dst = csr_src + EP;                             // EP
    float* as1     = (float*)(csr_dst + EP);                   // 4NN
    float* ad1     = as1 + (size_t)4 * NN;                     // 4NN
    unsigned short* h1b = (unsigned short*)(ad1 + (size_t)4 * NN);   // NN*256 bf16
    unsigned short* h1c = h1b + (size_t)256 * NN;              // NN*256 bf16
    unsigned short* h2b = h1c + (size_t)256 * NN;              // NN*64 bf16
    unsigned short* embb = h2b + (size_t)64 * NN;              // NN*64 bf16
    float* as2     = (float*)(embb + (size_t)64 * NN);         // NN
    float* ad2     = as2 + NN;                                 // NN
    unsigned short* w1h = (unsigned short*)(ad2 + NN);         // 256*128
    unsigned short* w1l = w1h + C1 * INC;
    unsigned short* w2h = w1l + C1 * INC;                      // 64*256
    unsigned short* w2l = w2h + HID * C1;
    unsigned short* wFh = w2l + HID * C1;                      // 8192
    unsigned short* wFl = wFh + PREP_N2;                       // 8192
    float* w1e     = (float*)(wFl + PREP_N2 + 64);             // 4*EP
    float* w2e     = w1e + (size_t)4 * EP;                     // EP
    int*   counts  = (int*)(w2e + EP + 64);                    // NN
    int*   bsum    = counts + NN + 64;                         // NSB
    int*   cursor  = bsum + NSB + 64;                          // NN

    // ---- CSR build + weight prep ----
    hipMemsetAsync(counts, 0, NN * sizeof(int), stream);
    prep_all<<<(PREP_TOT + EP + 255) / 256, 256, 0, stream>>>(
        mW1, W1, W2, ei, w1h, w1l, w2h, w2l, wFh, wFl, counts);
    scan_partial<<<NSB, SCHUNK, 0, stream>>>(counts, bsum);
    scan_top<<<1, 128, 0, stream>>>(bsum, rowptr);
    scan_final<<<NSB, SCHUNK, 0, stream>>>(counts, bsum, rowptr, cursor);
    csr_fill<<<(EP + 255) / 256, 256, 0, stream>>>(ei, cursor, csr_src, csr_dst);

    // ---- conv1 ----
    gemm1_mfma<<<dim3((NN + 63) / 64, 4), 256, 0, stream>>>(x, w1h, w1l, att_s1, att_d1,
                                                            h1b, as1, ad1);
    edge_w1k<<<(EP + 255) / 256, 256, 0, stream>>>(csr_src, csr_dst, as1, ad1, w1e);
    conv1_agg<<<NN / 8, 256, 0, stream>>>(rowptr, csr_src, w1e, h1b, b1, h1c);

    // ---- conv2 ----
    gemm2_mfma<<<(NN + 63) / 64, 256, 0, stream>>>(h1c, w2h, w2l, att_s2, att_d2,
                                                   h2b, as2, ad2);
    edge_w2k<<<(EP + 255) / 256, 256, 0, stream>>>(csr_src, csr_dst, as2, ad2, w2e);
    conv2_agg<<<NN / 8, 256, 0, stream>>>(rowptr, csr_src, w2e, h2b, b2, embb);

    // ---- edge MLP: 64 edges/wave ----
    edge_mlp_mfma<<<(NE / 64) / 4, 256, 0, stream>>>(ei, embb, stats, wFh, wFl, mW1,
                                                     mb1, mW2, mb2, out);
}

// Round 14
// 305.376 us; speedup vs baseline: 1.0428x; 1.0428x over previous
//
#include <hip/hip_runtime.h>
#include <math.h>

#define NN 50000
#define NE 800000
#define EP (NE + NN)        // edges including self loops
#define INC 128
#define HID 64
#define HEADS 4
#define C1 (HEADS * HID)    // 256
#define NEG 0.2f
#define EPSS 1e-16f

#define SCHUNK 512
#define NSB ((NN + SCHUNK - 1) / SCHUNK)   // 98

#define KP1 136             // gemm1 W1^T LDS stride
#define KP2 264             // gemm2 W2^T LDS stride
typedef __attribute__((ext_vector_type(8))) short bf16x8;
typedef __attribute__((ext_vector_type(4))) float f32x4;

// ---------- bf16 helpers ----------
__device__ __forceinline__ unsigned short f2bf(float f) {
    unsigned u = __float_as_uint(f);
    unsigned r = (u + 0x7FFFu + ((u >> 16) & 1u)) >> 16;
    return (unsigned short)r;
}
__device__ __forceinline__ float bf2f(unsigned short b) {
    return __uint_as_float(((unsigned)b) << 16);
}

// ================= CSR build (count merged into prep_all) =================
__global__ __launch_bounds__(SCHUNK) void scan_partial(const int* __restrict__ counts,
                                                       int* __restrict__ bsum) {
    __shared__ int lds[SCHUNK];
    int i = blockIdx.x * SCHUNK + threadIdx.x;
    lds[threadIdx.x] = (i < NN) ? counts[i] : 0;
    __syncthreads();
    for (int off = SCHUNK / 2; off > 0; off >>= 1) {
        if (threadIdx.x < off) lds[threadIdx.x] += lds[threadIdx.x + off];
        __syncthreads();
    }
    if (threadIdx.x == 0) bsum[blockIdx.x] = lds[0];
}

__global__ void scan_top(int* __restrict__ bsum, int* __restrict__ rowptr) {
    __shared__ int lds[NSB];
    int t = threadIdx.x;
    if (t < NSB) lds[t] = bsum[t];
    __syncthreads();
    if (t == 0) {
        int acc = 0;
        for (int i = 0; i < NSB; ++i) { int v = lds[i]; lds[i] = acc; acc += v; }
        rowptr[NN] = acc;   // == EP
    }
    __syncthreads();
    if (t < NSB) bsum[t] = lds[t];
}

__global__ __launch_bounds__(SCHUNK) void scan_final(const int* __restrict__ counts,
                                                     const int* __restrict__ bsum,
                                                     int* __restrict__ rowptr,
                                                     int* __restrict__ cursor) {
    __shared__ int lds[SCHUNK];
    int i = blockIdx.x * SCHUNK + threadIdx.x;
    int v = (i < NN) ? counts[i] : 0;
    lds[threadIdx.x] = v;
    __syncthreads();
    for (int off = 1; off < SCHUNK; off <<= 1) {
        int t = (threadIdx.x >= off) ? lds[threadIdx.x - off] : 0;
        __syncthreads();
        lds[threadIdx.x] += t;
        __syncthreads();
    }
    if (i < NN) {
        int excl = lds[threadIdx.x] - v + bsum[blockIdx.x];
        rowptr[i] = excl;
        cursor[i] = excl;
    }
}

__global__ void csr_fill(const int* __restrict__ ei, int* __restrict__ cursor,
                         int* __restrict__ csr_src, int* __restrict__ csr_dst) {
    int e = blockIdx.x * 256 + threadIdx.x;
    if (e >= EP) return;
    int s, d;
    if (e < NE) { s = ei[e]; d = ei[NE + e]; } else { s = d = e - NE; }
    int pos = atomicAdd(&cursor[d], 1);
    csr_src[pos] = s;
    csr_dst[pos] = d;
}

// ================= merged weight prep + edge count =================
#define PREP_N0 (C1 * INC)
#define PREP_N1 (HID * C1)
#define PREP_N2 (4 * 4 * 64 * 8)   // 8192
#define PREP_TOT (PREP_N0 + PREP_N1 + PREP_N2)
__global__ void prep_all(const float* __restrict__ mW1, const float* __restrict__ W1,
                         const float* __restrict__ W2, const int* __restrict__ ei,
                         unsigned short* __restrict__ w1h, unsigned short* __restrict__ w1l,
                         unsigned short* __restrict__ w2h, unsigned short* __restrict__ w2l,
                         unsigned short* __restrict__ wFh, unsigned short* __restrict__ wFl,
                         int* __restrict__ counts) {
    int i = blockIdx.x * 256 + threadIdx.x;
    if (i < PREP_N0) {
        int c = i >> 7, k = i & 127;
        float f = W1[k * C1 + c];
        unsigned short h = f2bf(f);
        w1h[i] = h; w1l[i] = f2bf(f - bf2f(h));
        return;
    }
    i -= PREP_N0;
    if (i < PREP_N1) {
        int c = i >> 8, k = i & 255;
        float f = W2[k * HID + c];
        unsigned short h = f2bf(f);
        w2h[i] = h; w2l[i] = f2bf(f - bf2f(h));
        return;
    }
    i -= PREP_N1;
    if (i < PREP_N2) {
        int kk = i >> 11;
        int ct = (i >> 9) & 3;
        int l  = (i >> 3) & 63;
        int j  = i & 7;
        int cl = l & 15, g = l >> 4;
        int k   = kk * 32 + g * 8 + j;      // < 128
        int col = ct * 16 + cl;
        float f = mW1[k * 64 + col];
        unsigned short h = f2bf(f);
        wFh[i] = h;
        wFl[i] = f2bf(f - bf2f(h));
        return;
    }
    i -= PREP_N2;
    if (i < EP) {
        int d = (i < NE) ? ei[NE + i] : (i - NE);
        atomicAdd(&counts[d], 1);
    }
}

// ================= edge softmax weights (precomputed once per edge) ==========
__global__ void edge_w1k(const int* __restrict__ csr_src, const int* __restrict__ csr_dst,
                         const float* __restrict__ as1, const float* __restrict__ ad1,
                         float* __restrict__ w1e) {
    int i = blockIdx.x * 256 + threadIdx.x;
    if (i >= EP) return;
    int s = csr_src[i], d = csr_dst[i];
    float4 a = *(const float4*)(as1 + s * 4);
    float4 b = *(const float4*)(ad1 + d * 4);
    float4 o;
    float t;
    t = a.x + b.x; t = t > 0.f ? t : NEG * t; o.x = __expf(t);
    t = a.y + b.y; t = t > 0.f ? t : NEG * t; o.y = __expf(t);
    t = a.z + b.z; t = t > 0.f ? t : NEG * t; o.z = __expf(t);
    t = a.w + b.w; t = t > 0.f ? t : NEG * t; o.w = __expf(t);
    *(float4*)(w1e + (size_t)i * 4) = o;
}

__global__ void edge_w2k(const int* __restrict__ csr_src, const int* __restrict__ csr_dst,
                         const float* __restrict__ as2, const float* __restrict__ ad2,
                         float* __restrict__ w2e) {
    int i = blockIdx.x * 256 + threadIdx.x;
    if (i >= EP) return;
    float t = as2[csr_src[i]] + ad2[csr_dst[i]];
    t = t > 0.f ? t : NEG * t;
    w2e[i] = __expf(t);
}

// ================= GEMM1 via split-bf16 MFMA + att1 epilogue =================
__global__ __launch_bounds__(256) void gemm1_mfma(const float* __restrict__ x,
                                                  const unsigned short* __restrict__ w1h,
                                                  const unsigned short* __restrict__ w1l,
                                                  const float* __restrict__ att_s,
                                                  const float* __restrict__ att_d,
                                                  unsigned short* __restrict__ h1b,
                                                  float* __restrict__ as1,
                                                  float* __restrict__ ad1) {
    __shared__ unsigned short wH[64 * KP1];
    __shared__ unsigned short wL[64 * KP1];
    const int tid = threadIdx.x;
    const int n0 = blockIdx.x * 64;
    const int q  = blockIdx.y;

    for (int idx = tid; idx < 64 * 16; idx += 256) {
        int col = idx >> 4, ch = idx & 15;
        *(bf16x8*)(wH + col * KP1 + ch * 8) =
            *(const bf16x8*)(w1h + ((q * 64 + col) << 7) + ch * 8);
        *(bf16x8*)(wL + col * KP1 + ch * 8) =
            *(const bf16x8*)(w1l + ((q * 64 + col) << 7) + ch * 8);
    }

    const int w = tid >> 6, l = tid & 63;
    const int cl = l & 15, g = l >> 4, g8 = g * 8;
    const int na = min(n0 + w * 16 + cl, NN - 1);

    bf16x8 aH[4], aL[4];
#pragma unroll
    for (int kk = 0; kk < 4; ++kk) {
        const float* ap = x + (size_t)na * INC + kk * 32 + g8;
        float4 v0 = *(const float4*)ap;
        float4 v1 = *(const float4*)(ap + 4);
        float vv[8] = {v0.x, v0.y, v0.z, v0.w, v1.x, v1.y, v1.z, v1.w};
#pragma unroll
        for (int j = 0; j < 8; ++j) {
            unsigned short h = f2bf(vv[j]);
            aH[kk][j] = (short)h;
            aL[kk][j] = (short)f2bf(vv[j] - bf2f(h));
        }
    }

    f32x4 acc[4];
#pragma unroll
    for (int ct = 0; ct < 4; ++ct) acc[ct] = (f32x4){0.f, 0.f, 0.f, 0.f};

    __syncthreads();

#pragma unroll
    for (int kk = 0; kk < 4; ++kk) {
        const int ko = kk * 32 + g8;
#pragma unroll
        for (int ct = 0; ct < 4; ++ct) {
            const bf16x8 bH = *(const bf16x8*)(wH + (ct * 16 + cl) * KP1 + ko);
            const bf16x8 bL = *(const bf16x8*)(wL + (ct * 16 + cl) * KP1 + ko);
            acc[ct] = __builtin_amdgcn_mfma_f32_16x16x32_bf16(aH[kk], bH, acc[ct], 0, 0, 0);
            acc[ct] = __builtin_amdgcn_mfma_f32_16x16x32_bf16(aH[kk], bL, acc[ct], 0, 0, 0);
            acc[ct] = __builtin_amdgcn_mfma_f32_16x16x32_bf16(aL[kk], bH, acc[ct], 0, 0, 0);
        }
    }

    float asc[4], adc[4];
#pragma unroll
    for (int ct = 0; ct < 4; ++ct) {
        asc[ct] = att_s[q * 64 + ct * 16 + cl];
        adc[ct] = att_d[q * 64 + ct * 16 + cl];
    }

#pragma unroll
    for (int reg = 0; reg < 4; ++reg) {
        const int nd = n0 + w * 16 + g * 4 + reg;
        float sa = 0.f, sd = 0.f;
#pragma unroll
        for (int ct = 0; ct < 4; ++ct) {
            sa += acc[ct][reg] * asc[ct];
            sd += acc[ct][reg] * adc[ct];
        }
#pragma unroll
        for (int off = 8; off > 0; off >>= 1) {
            sa += __shfl_xor(sa, off);
            sd += __shfl_xor(sd, off);
        }
        if (nd < NN) {
#pragma unroll
            for (int ct = 0; ct < 4; ++ct)
                h1b[(size_t)nd * C1 + q * 64 + ct * 16 + cl] = f2bf(acc[ct][reg]);
            if (cl == 0) { as1[nd * 4 + q] = sa; ad1[nd * 4 + q] = sd; }
        }
    }
}

// ================= GEMM2: bf16-A x split-bf16-W MFMA + att2 epilogue =========
__global__ __launch_bounds__(256) void gemm2_mfma(const unsigned short* __restrict__ h1c,
                                                  const unsigned short* __restrict__ w2h,
                                                  const unsigned short* __restrict__ w2l,
                                                  const float* __restrict__ att_s,
                                                  const float* __restrict__ att_d,
                                                  unsigned short* __restrict__ h2b,
                                                  float* __restrict__ as2,
                                                  float* __restrict__ ad2) {
    __shared__ unsigned short wH[64 * KP2];
    __shared__ unsigned short wL[64 * KP2];
    const int tid = threadIdx.x;
    const int n0 = blockIdx.x * 64;

    for (int idx = tid; idx < 64 * 32; idx += 256) {
        int col = idx >> 5, ch = idx & 31;
        *(bf16x8*)(wH + col * KP2 + ch * 8) =
            *(const bf16x8*)(w2h + ((col) << 8) + ch * 8);
        *(bf16x8*)(wL + col * KP2 + ch * 8) =
            *(const bf16x8*)(w2l + ((col) << 8) + ch * 8);
    }

    const int w = tid >> 6, l = tid & 63;
    const int cl = l & 15, g = l >> 4, g8 = g * 8;
    const int na = min(n0 + w * 16 + cl, NN - 1);

    f32x4 acc[4];
#pragma unroll
    for (int ct = 0; ct < 4; ++ct) acc[ct] = (f32x4){0.f, 0.f, 0.f, 0.f};

    __syncthreads();

#pragma unroll
    for (int kk = 0; kk < 8; ++kk) {
        const bf16x8 aH = *(const bf16x8*)(h1c + (size_t)na * C1 + kk * 32 + g8);
        const int ko = kk * 32 + g8;
#pragma unroll
        for (int ct = 0; ct < 4; ++ct) {
            const bf16x8 bH = *(const bf16x8*)(wH + (ct * 16 + cl) * KP2 + ko);
            const bf16x8 bL = *(const bf16x8*)(wL + (ct * 16 + cl) * KP2 + ko);
            acc[ct] = __builtin_amdgcn_mfma_f32_16x16x32_bf16(aH, bH, acc[ct], 0, 0, 0);
            acc[ct] = __builtin_amdgcn_mfma_f32_16x16x32_bf16(aH, bL, acc[ct], 0, 0, 0);
        }
    }

    float asc[4], adc[4];
#pragma unroll
    for (int ct = 0; ct < 4; ++ct) {
        asc[ct] = att_s[ct * 16 + cl];
        adc[ct] = att_d[ct * 16 + cl];
    }

#pragma unroll
    for (int reg = 0; reg < 4; ++reg) {
        const int nd = n0 + w * 16 + g * 4 + reg;
        float sa = 0.f, sd = 0.f;
#pragma unroll
        for (int ct = 0; ct < 4; ++ct) {
            sa += acc[ct][reg] * asc[ct];
            sd += acc[ct][reg] * adc[ct];
        }
#pragma unroll
        for (int off = 8; off > 0; off >>= 1) {
            sa += __shfl_xor(sa, off);
            sd += __shfl_xor(sd, off);
        }
        if (nd < NN) {
#pragma unroll
            for (int ct = 0; ct < 4; ++ct)
                h2b[(size_t)nd * HID + ct * 16 + cl] = f2bf(acc[ct][reg]);
            if (cl == 0) { as2[nd] = sa; ad2[nd] = sd; }
        }
    }
}

// ================= conv1 aggregate: 2 nodes/wave, precomputed weights =========
__global__ __launch_bounds__(256) void conv1_agg(const int* __restrict__ rowptr,
                                                 const int* __restrict__ csr_src,
                                                 const float* __restrict__ w1e,
                                                 const unsigned short* __restrict__ h1b,
                                                 const float* __restrict__ b1,
                                                 unsigned short* __restrict__ h1c) {
    const int tid  = threadIdx.x;
    const int wid  = tid >> 6;
    const int l    = tid & 63;
    const int half = l >> 5;
    const int l32  = l & 31;
    const int node = blockIdx.x * 8 + wid * 2 + half;   // NN % 8 == 0
    const int hd   = l32 >> 3;
    const int beg = rowptr[node], end = rowptr[node + 1];

    float acc[8] = {0.f, 0.f, 0.f, 0.f, 0.f, 0.f, 0.f, 0.f};
    float sm = 0.f;
#pragma unroll 2
    for (int i = beg; i < end; ++i) {
        int s = csr_src[i];
        float w = w1e[(size_t)i * 4 + hd];
        bf16x8 hv = *(const bf16x8*)(h1b + (size_t)s * C1 + l32 * 8);
#pragma unroll
        for (int j = 0; j < 8; ++j)
            acc[j] += w * bf2f((unsigned short)hv[j]);
        sm += w;
    }
    const float rden = 1.f / (sm + EPSS);

    const float* bp = b1 + l32 * 8;
    bf16x8 ob;
#pragma unroll
    for (int j = 0; j < 8; ++j) {
        float o = acc[j] * rden + bp[j];
        o = o > 0.f ? o : (__expf(o) - 1.f);
        ob[j] = (short)f2bf(o);
    }
    *(bf16x8*)(h1c + (size_t)node * C1 + l32 * 8) = ob;
}

// ================= conv2 aggregate: 2 nodes/wave, precomputed weights =========
__global__ __launch_bounds__(256) void conv2_agg(const int* __restrict__ rowptr,
                                                 const int* __restrict__ csr_src,
                                                 const float* __restrict__ w2e,
                                                 const unsigned short* __restrict__ h2b,
                                                 const float* __restrict__ b2,
                                                 unsigned short* __restrict__ embb) {
    const int tid  = threadIdx.x;
    const int wid  = tid >> 6;
    const int l    = tid & 63;
    const int half = l >> 5;
    const int l32  = l & 31;
    const int node = blockIdx.x * 8 + wid * 2 + half;
    const int beg = rowptr[node], end = rowptr[node + 1];

    float a0 = 0.f, a1 = 0.f, sm = 0.f;
#pragma unroll 2
    for (int i = beg; i < end; ++i) {
        int s = csr_src[i];
        float w = w2e[i];
        unsigned hv = *(const unsigned*)(h2b + (size_t)s * HID + l32 * 2);
        a0 += w * bf2f((unsigned short)(hv & 0xFFFF));
        a1 += w * bf2f((unsigned short)(hv >> 16));
        sm += w;
    }
    const float rden = 1.f / (sm + EPSS);
    float o0 = a0 * rden + b2[l32 * 2];
    float o1 = a1 * rden + b2[l32 * 2 + 1];
    unsigned outw = (unsigned)f2bf(o0) | ((unsigned)f2bf(o1) << 16);
    *(unsigned*)(embb + (size_t)node * HID + l32 * 2) = outw;
}

// ================= edge MLP: LDS fragment-linear B, 32 edges/wave =============
// B staged in LDS verbatim (fragment-linear): every B read is 64 lanes x 16B
// contiguous (conflict-free ds_read_b128). 2 sub-tiles share each B read.
// Small register set (acc 32 + a 32 + consts) -> no spills, high occupancy.
__global__ __launch_bounds__(256) void edge_mlp_mfma(const int* __restrict__ ei,
                                                     const unsigned short* __restrict__ embb,
                                                     const float* __restrict__ stats,
                                                     const unsigned short* __restrict__ wFh,
                                                     const unsigned short* __restrict__ wFl,
                                                     const float* __restrict__ mW1,
                                                     const float* __restrict__ mb1,
                                                     const float* __restrict__ mW2,
                                                     const float* __restrict__ mb2,
                                                     float* __restrict__ out) {
    __shared__ unsigned short sH[PREP_N2];   // 16 KB
    __shared__ unsigned short sL[PREP_N2];   // 16 KB
    const int tid = threadIdx.x;
    for (int idx = tid; idx < PREP_N2 / 8; idx += 256) {
        ((float4*)sH)[idx] = ((const float4*)wFh)[idx];
        ((float4*)sL)[idx] = ((const float4*)wFl)[idx];
    }

    const int l  = tid & 63;
    const int cl = l & 15;
    const int g  = l >> 4;
    const int g8 = g * 8;

    // epilogue constants
    float w1s0[4], w1s1[4], w1s2[4], bia[4], w2a[4], w2b[4];
#pragma unroll
    for (int ct = 0; ct < 4; ++ct) {
        const int col = ct * 16 + cl;
        w1s0[ct] = mW1[128 * 64 + col];
        w1s1[ct] = mW1[129 * 64 + col];
        w1s2[ct] = mW1[130 * 64 + col];
        bia[ct] = mb1[col];
        w2a[ct] = mW2[col * 2 + 0];
        w2b[ct] = mW2[col * 2 + 1];
    }
    const float ob0 = mb2[0], ob1 = mb2[1];

    const int t = blockIdx.x * 4 + (tid >> 6);   // 32-edge tile id, 0..24999

    // A gather: 2 sub-tiles x 4 k-chunks
    bf16x8 a[2][4];
#pragma unroll
    for (int s = 0; s < 2; ++s) {
        const int ge_a = t * 32 + s * 16 + cl;
        const int rn = ei[ge_a];
        const int cn = ei[NE + ge_a];
        const unsigned short* rp = embb + (size_t)rn * HID;
        const unsigned short* cp = embb + (size_t)cn * HID;
        a[s][0] = *(const bf16x8*)(rp + g8);
        a[s][1] = *(const bf16x8*)(rp + 32 + g8);
        a[s][2] = *(const bf16x8*)(cp + g8);
        a[s][3] = *(const bf16x8*)(cp + 32 + g8);
    }

    f32x4 acc[2][4];
#pragma unroll
    for (int s = 0; s < 2; ++s)
#pragma unroll
        for (int ct = 0; ct < 4; ++ct)
            acc[s][ct] = (f32x4){bia[ct], bia[ct], bia[ct], bia[ct]};

    __syncthreads();

#pragma unroll
    for (int kk = 0; kk < 4; ++kk) {
#pragma unroll
        for (int ct = 0; ct < 4; ++ct) {
            const int fo = ((kk * 4 + ct) * 64 + l) * 8;
            const bf16x8 bH = *(const bf16x8*)(sH + fo);
            const bf16x8 bL = *(const bf16x8*)(sL + fo);
#pragma unroll
            for (int s = 0; s < 2; ++s) {
                acc[s][ct] = __builtin_amdgcn_mfma_f32_16x16x32_bf16(a[s][kk], bH, acc[s][ct], 0, 0, 0);
                acc[s][ct] = __builtin_amdgcn_mfma_f32_16x16x32_bf16(a[s][kk], bL, acc[s][ct], 0, 0, 0);
            }
        }
    }

    // epilogue: stats (exact f32) + layer 2 + 16-lane reduce + store
#pragma unroll
    for (int s = 0; s < 2; ++s) {
        const float* sp = stats + (size_t)(t * 32 + s * 16 + g * 4) * 3;
        float4 s0 = *(const float4*)(sp);
        float4 s1 = *(const float4*)(sp + 4);
        float4 s2 = *(const float4*)(sp + 8);
        float cst[12] = {s0.x, s0.y, s0.z, s0.w, s1.x, s1.y, s1.z, s1.w,
                         s2.x, s2.y, s2.z, s2.w};
#pragma unroll
        for (int reg = 0; reg < 4; ++reg) {
            float p0 = 0.f, p1 = 0.f;
#pragma unroll
            for (int ct = 0; ct < 4; ++ct) {
                float h = acc[s][ct][reg]
                        + cst[reg * 3 + 0] * w1s0[ct]
                        + cst[reg * 3 + 1] * w1s1[ct]
                        + cst[reg * 3 + 2] * w1s2[ct];
                h = fmaxf(h, 0.f);
                p0 += h * w2a[ct];
                p1 += h * w2b[ct];
            }
#pragma unroll
            for (int off = 8; off > 0; off >>= 1) {
                p0 += __shfl_xor(p0, off);
                p1 += __shfl_xor(p1, off);
            }
            if (cl == 0) {
                const int ge = t * 32 + s * 16 + g * 4 + reg;
                *(float2*)(out + (size_t)ge * 2) = make_float2(p0 + ob0, p1 + ob1);
            }
        }
    }
}

// ================= launcher =================
extern "C" void kernel_launch(void* const* d_in, const int* in_sizes, int n_in,
                              void* d_out, int out_size, void* d_ws, size_t ws_size,
                              hipStream_t stream) {
    const float* x      = (const float*)d_in[0];
    const int*   ei     = (const int*)d_in[1];
    const float* stats  = (const float*)d_in[2];
    const float* W1     = (const float*)d_in[3];
    const float* att_s1 = (const float*)d_in[4];
    const float* att_d1 = (const float*)d_in[5];
    const float* b1     = (const float*)d_in[6];
    const float* W2     = (const float*)d_in[7];
    const float* att_s2 = (const float*)d_in[8];
    const float* att_d2 = (const float*)d_in[9];
    const float* b2     = (const float*)d_in[10];
    const float* mW1    = (const float*)d_in[11];
    const float* mb1    = (const float*)d_in[12];
    const float* mW2    = (const float*)d_in[13];
    const float* mb2    = (const float*)d_in[14];
    float* out = (float*)d_out;
    float* ws  = (float*)d_ws;

    // f32-word-offset layout (no aliasing)
    int*   rowptr  = (int*)ws;                                 // NN+16
    int*   csr_src = rowptr + NN + 16;                         // EP
    int*   csr_dst = csr_src + EP;                             // EP
    float* as1     = (float*)(csr_dst + EP);                   // 4NN
    float* ad1     = as1 + (size_t)4 * NN;                     // 4NN
    unsigned short* h1b = (unsigned short*)(ad1 + (size_t)4 * NN);   // NN*256 bf16
    unsigned short* h1c = h1b + (size_t)256 * NN;              // NN*256 bf16
    unsigned short* h2b = h1c + (size_t)256 * NN;              // NN*64 bf16
    unsigned short* embb = h2b + (size_t)64 * NN;              // NN*64 bf16
    float* as2     = (float*)(embb + (size_t)64 * NN);         // NN
    float* ad2     = as2 + NN;                                 // NN
    unsigned short* w1h = (unsigned short*)(ad2 + NN);         // 256*128
    unsigned short* w1l = w1h + C1 * INC;
    unsigned short* w2h = w1l + C1 * INC;                      // 64*256
    unsigned short* w2l = w2h + HID * C1;
    unsigned short* wFh = w2l + HID * C1;                      // 8192
    unsigned short* wFl = wFh + PREP_N2;                       // 8192
    float* w1e     = (float*)(wFl + PREP_N2 + 64);             // 4*EP
    float* w2e     = w1e + (size_t)4 * EP;                     // EP
    int*   counts  = (int*)(w2e + EP + 64);                    // NN
    int*   bsum    = counts + NN + 64;                         // NSB
    int*   cursor  = bsum + NSB + 64;                          // NN

    // ---- CSR build + weight prep ----
    hipMemsetAsync(counts, 0, NN * sizeof(int), stream);
    prep_all<<<(PREP_TOT + EP + 255) / 256, 256, 0, stream>>>(
        mW1, W1, W2, ei, w1h, w1l, w2h, w2l, wFh, wFl, counts);
    scan_partial<<<NSB, SCHUNK, 0, stream>>>(counts, bsum);
    scan_top<<<1, 128, 0, stream>>>(bsum, rowptr);
    scan_final<<<NSB, SCHUNK, 0, stream>>>(counts, bsum, rowptr, cursor);
    csr_fill<<<(EP + 255) / 256, 256, 0, stream>>>(ei, cursor, csr_src, csr_dst);

    // ---- conv1 ----
    gemm1_mfma<<<dim3((NN + 63) / 64, 4), 256, 0, stream>>>(x, w1h, w1l, att_s1, att_d1,
                                                            h1b, as1, ad1);
    edge_w1k<<<(EP + 255) / 256, 256, 0, stream>>>(csr_src, csr_dst, as1, ad1, w1e);
    conv1_agg<<<NN / 8, 256, 0, stream>>>(rowptr, csr_src, w1e, h1b, b1, h1c);

    // ---- conv2 ----
    gemm2_mfma<<<(NN + 63) / 64, 256, 0, stream>>>(h1c, w2h, w2l, att_s2, att_d2,
                                                   h2b, as2, ad2);
    edge_w2k<<<(EP + 255) / 256, 256, 0, stream>>>(csr_src, csr_dst, as2, ad2, w2e);
    conv2_agg<<<NN / 8, 256, 0, stream>>>(rowptr, csr_src, w2e, h2b, b2, embb);

    // ---- edge MLP: 32 edges/wave, LDS-staged fragment-linear B ----
    edge_mlp_mfma<<<(NE / 32) / 4, 256, 0, stream>>>(ei, embb, stats, wFh, wFl, mW1,
                                                     mb1, mW2, mb2, out);
}